// Round 9
// baseline (1432.349 us; speedup 1.0000x reference)
//
#include <hip/hip_runtime.h>
#include <math.h>

#define B 256
#define S 100
#define H 512
#define E 512
#define R 50
#define NC 5
#define H3 1536

__device__ __forceinline__ float selu_f(float x){
    return x > 0.0f ? 1.0507009873554805f * x
                    : 1.7580993408473766f * expm1f(x);   // scale*alpha
}
__device__ __forceinline__ float wred_sum(float v){
    #pragma unroll
    for (int o = 32; o > 0; o >>= 1) v += __shfl_xor(v, o);
    return v;
}
__device__ __forceinline__ float wred_maxf(float v){
    #pragma unroll
    for (int o = 32; o > 0; o >>= 1) v = fmaxf(v, __shfl_xor(v, o));
    return v;
}

// ============== 32x128 tiled f32 GEMM, 2x8/thread, conflict-aware col map ==============
// C[M,N] = (seluA? selu(A) : A)[M,K(range)] @ W[N,:K]^T (+bias[n]) (+addm[m,n])
// per-thread cols: {tx*4..+3} and {64+tx*4..+3}  -> 2-way LDS conflict max
struct GSmem {
    alignas(16) float As[16][36];    // [k][m]
    alignas(16) float Ws[16][132];   // [k][n]
};

__device__ __forceinline__ void gemm32(
    GSmem& sm,
    const float* __restrict__ A, int lda, int M,
    const float* __restrict__ W, int ldw,
    const float* __restrict__ bias,
    const float* __restrict__ addm, int ldadd,
    float* __restrict__ C, int ldc,
    int N, int m0, int n0, int k0beg, int k0end, int seluA)
{
    const int t  = threadIdx.x;
    const int tx = t & 15;            // n-group
    const int ty = t >> 4;            // m-group (2 rows)
    const int lm = t >> 3,  lk  = (t & 7) << 1;   // A loader: float2
    const int lw = t >> 1,  lkw = (t & 1) << 3;   // W loader: 2x float4
    int am = m0 + lm; if (am >= M) am = M - 1;    // row clamp (for M not mult of 32)
    const float* Ap = A + (size_t)am * lda + lk;
    const int nw = n0 + lw;
    const float* Wp = W + (size_t)nw * ldw + lkw;
    const bool wok = (nw < N);
    const float4 f40 = make_float4(0.f, 0.f, 0.f, 0.f);

    float2 ar = *(const float2*)(Ap + k0beg);
    if (seluA){ ar.x = selu_f(ar.x); ar.y = selu_f(ar.y); }
    float4 w0 = wok ? *(const float4*)(Wp + k0beg)     : f40;
    float4 w1 = wok ? *(const float4*)(Wp + k0beg + 4) : f40;

    float acc[2][8] = {};
    for (int k0 = k0beg; k0 < k0end; k0 += 16){
        if (k0 != k0beg) __syncthreads();
        sm.As[lk+0][lm] = ar.x; sm.As[lk+1][lm] = ar.y;
        sm.Ws[lkw+0][lw] = w0.x; sm.Ws[lkw+1][lw] = w0.y;
        sm.Ws[lkw+2][lw] = w0.z; sm.Ws[lkw+3][lw] = w0.w;
        sm.Ws[lkw+4][lw] = w1.x; sm.Ws[lkw+5][lw] = w1.y;
        sm.Ws[lkw+6][lw] = w1.z; sm.Ws[lkw+7][lw] = w1.w;
        __syncthreads();
        if (k0 + 16 < k0end){
            ar = *(const float2*)(Ap + k0 + 16);
            if (seluA){ ar.x = selu_f(ar.x); ar.y = selu_f(ar.y); }
            w0 = wok ? *(const float4*)(Wp + k0 + 16)     : f40;
            w1 = wok ? *(const float4*)(Wp + k0 + 16 + 4) : f40;
        }
        #pragma unroll
        for (int kk = 0; kk < 16; ++kk){
            const float2 av  = *(const float2*)&sm.As[kk][ty*2];
            const float4 wv0 = *(const float4*)&sm.Ws[kk][tx*4];
            const float4 wv1 = *(const float4*)&sm.Ws[kk][tx*4 + 64];
            const float aa[2] = {av.x, av.y};
            const float bb[8] = {wv0.x, wv0.y, wv0.z, wv0.w, wv1.x, wv1.y, wv1.z, wv1.w};
            #pragma unroll
            for (int i = 0; i < 2; ++i)
                #pragma unroll
                for (int j = 0; j < 8; ++j)
                    acc[i][j] += aa[i] * bb[j];
        }
    }
    #pragma unroll
    for (int i = 0; i < 2; ++i){
        const int m = m0 + ty*2 + i;
        if (m < M){
            #pragma unroll
            for (int j = 0; j < 8; ++j){
                const int n = n0 + ((j < 4) ? (tx*4 + j) : (64 + tx*4 + j - 4));
                if (n < N){
                    float vv = acc[i][j];
                    if (bias) vv += bias[n];
                    if (addm) vv += addm[(size_t)m * ldadd + n];
                    C[(size_t)m * ldc + n] = vv;
                }
            }
        }
    }
}

// generic batched GEMM: grid (ceil(N/128), ceil(M/32), batch)
__global__ __launch_bounds__(256) void k_gemm(
    const float* A, int lda, long long sA, int M,
    const float* W, int ldw, long long sW,
    const float* bias, long long sBias,
    const float* addm, int ldadd, long long sAddm,
    float* C, int ldc, long long sC,
    int N, int K, int seluA)
{
    __shared__ GSmem sm;
    const int z = blockIdx.z;
    gemm32(sm,
           A + (size_t)z * sA, lda, M,
           W + (size_t)z * sW, ldw,
           bias ? bias + (size_t)z * sBias : nullptr,
           addm ? addm + (size_t)z * sAddm : nullptr, ldadd,
           C + (size_t)z * sC, ldc,
           N, blockIdx.y * 32, blockIdx.x * 128, 0, K, seluA);
}

// per-step GEMM, split-K=2.
// giOn=1: grid (24, 8, 2): x<12 gi tiles, x>=12 gh tiles.  giOn=0: grid (12, 8, 2): gh only.
__global__ __launch_bounds__(256) void k_gru2(
    const float* emb, const float* h,
    const float* Wihc, const float* Whh,
    const float* gixc, const float* bhh,
    float* gi0, float* gi1, float* gh0, float* gh1, int giOn)
{
    __shared__ GSmem sm;
    int xt = blockIdx.x;
    const int m0 = blockIdx.y * 32;
    const int z  = blockIdx.z;
    const int kb = z * 256, ke = kb + 256;
    if (giOn && xt < 12){
        gemm32(sm, emb, E, B, Wihc, E, nullptr,
               (z == 0) ? gixc : nullptr, H3,
               (z == 0) ? gi0 : gi1, H3,
               H3, m0, xt * 128, kb, ke, 0);
    } else {
        if (giOn) xt -= 12;
        gemm32(sm, h, H, B, Whh, H,
               (z == 0) ? bhh : nullptr, nullptr, 0,
               (z == 0) ? gh0 : gh1, H3,
               H3, m0, xt * 128, kb, ke, 0);
    }
}

// ================= attention context (loop-invariant) =================
__global__ __launch_bounds__(256) void k_ctx(const float* __restrict__ enc,
                                             const float* __restrict__ W_attn,
                                             float* __restrict__ ctx)
{
    __shared__ float sc[128];
    __shared__ float red[128];
    const int b = blockIdx.x;
    const int t = threadIdx.x;
    const int wv = t >> 6, ln = t & 63;
    const float* eb = enc + (size_t)b * S * H;
    const float* wa = W_attn + H;
    for (int s = wv; s < S; s += 4){
        const float* es = eb + (size_t)s * H;
        float a = 0.f;
        #pragma unroll
        for (int u = 0; u < H/64; ++u) a += es[ln + 64*u] * wa[ln + 64*u];
        a = wred_sum(a);
        if (ln == 0) sc[s] = a;
    }
    __syncthreads();
    float vm = (t < S) ? sc[t] : -INFINITY;
    if (t < 128) red[t] = vm;
    __syncthreads();
    for (int st = 64; st > 0; st >>= 1){
        if (t < st) red[t] = fmaxf(red[t], red[t + st]);
        __syncthreads();
    }
    const float m = red[0];
    __syncthreads();
    float e = (t < S) ? expf(sc[t] - m) : 0.f;
    if (t < 128) red[t] = e;
    __syncthreads();
    for (int st = 64; st > 0; st >>= 1){
        if (t < st) red[t] += red[t + st];
        __syncthreads();
    }
    const float sum = red[0];
    __syncthreads();
    if (t < S) sc[t] = e / sum;
    __syncthreads();
    for (int hh = t; hh < H; hh += 256){
        float a = 0.f;
        for (int s = 0; s < S; ++s) a += sc[s] * eb[(size_t)s * H + hh];
        ctx[(size_t)b * H + hh] = a;
    }
}

// ================= Wc1^T (for the Wihc fold) =================
__global__ __launch_bounds__(256) void k_transpose(const float* __restrict__ Wc,
                                                   float* __restrict__ WT)
{
    __shared__ float tile[64][65];
    const int bx = blockIdx.x * 64;   // k range
    const int by = blockIdx.y * 64;   // j range
    const int t = threadIdx.x;
    const int c4 = (t & 15) * 4, rg = t >> 4;
    for (int r = 0; r < 64; r += 16){
        float4 v = *(const float4*)(Wc + (size_t)(by + rg + r) * (H + E) + bx + c4);
        tile[rg + r][c4+0] = v.x; tile[rg + r][c4+1] = v.y;
        tile[rg + r][c4+2] = v.z; tile[rg + r][c4+3] = v.w;
    }
    __syncthreads();
    for (int r = 0; r < 64; r += 16){
        WT[(size_t)(bx + rg + r) * E + by + c4 + 0] = tile[c4+0][rg + r];
        WT[(size_t)(bx + rg + r) * E + by + c4 + 1] = tile[c4+1][rg + r];
        WT[(size_t)(bx + rg + r) * E + by + c4 + 2] = tile[c4+2][rg + r];
        WT[(size_t)(bx + rg + r) * E + by + c4 + 3] = tile[c4+3][rg + r];
    }
}

// ================= init: emb = sos, h0 = 0.5*dec =================
__global__ __launch_bounds__(256) void k_init(
    const float* __restrict__ sos, const float* __restrict__ dec,
    float* __restrict__ emb, float* __restrict__ h0)
{
    const int idx = blockIdx.x * 256 + threadIdx.x;
    emb[idx] = sos[idx & (E - 1)];
    h0[idx]  = 0.5f * dec[idx];
}

// ====== fused rel step: combine(+splitK) + 51 logits + softmax + argmax + NEXT-gi write ======
__global__ __launch_bounds__(256) void k_rel_fused(
    const float* __restrict__ gi0, const float* __restrict__ gi1,
    const float* __restrict__ gh0, const float* __restrict__ gh1,
    const float* __restrict__ hold,
    const float* __restrict__ Wp, const float* __restrict__ bp,
    const float* __restrict__ We, const float* __restrict__ be,
    const float* __restrict__ rel_gi_c,    // [64, H3] precomputed rel_emb @ Wihc^T
    const float* __restrict__ gixc_c,      // [B, H3]
    float* __restrict__ gi_next,           // gi0 buffer: full-K gi for next step
    float* __restrict__ out_rel, int c,
    float* __restrict__ out_act,
    float* __restrict__ hnew_out)
{
    __shared__ float hn[H];
    __shared__ float logits[R + 1];
    __shared__ int   act_sh;
    const int b = blockIdx.x, t = threadIdx.x;
    const int wvi = t >> 6, ln = t & 63;
    const size_t gbase = (size_t)b * H3;
    for (int g = t; g < H; g += 256){
        const float ir  = gi0[gbase + g]       + gi1[gbase + g];
        const float hr  = gh0[gbase + g]       + gh1[gbase + g];
        const float iz  = gi0[gbase + H + g]   + gi1[gbase + H + g];
        const float hz  = gh0[gbase + H + g]   + gh1[gbase + H + g];
        const float in_ = gi0[gbase + 2*H + g] + gi1[gbase + 2*H + g];
        const float hnn = gh0[gbase + 2*H + g] + gh1[gbase + 2*H + g];
        const float r = 1.f / (1.f + expf(-(ir + hr)));
        const float z = 1.f / (1.f + expf(-(iz + hz)));
        const float n = tanhf(in_ + r * hnn);
        const float hv = (1.f - z) * n + z * hold[(size_t)b * H + g];
        hn[g] = hv;
        hnew_out[(size_t)b * H + g] = hv;
    }
    __syncthreads();
    for (int i = wvi; i < R + 1; i += 4){
        const float* wr = (i < R) ? Wp + (size_t)i * H : We;
        float a = 0.f;
        #pragma unroll
        for (int u = 0; u < H/64; ++u) a += hn[ln + 64*u] * wr[ln + 64*u];
        a = wred_sum(a);
        if (ln == 0) logits[i] = a + (i < R ? bp[i] : be[0]);
    }
    __syncthreads();
    if (wvi == 0){
        const float v = (ln < R + 1) ? logits[ln] : -INFINITY;
        const float m = wred_maxf(v);
        const float p = v - m;
        const float e = (ln < R + 1) ? expf(p) : 0.f;
        const float lse = logf(wred_sum(e));
        const float q = p - lse;
        float bv = q; int bi = ln;
        #pragma unroll
        for (int o = 32; o > 0; o >>= 1){
            float ov = __shfl_xor(bv, o);
            int   oi = __shfl_xor(bi, o);
            if (ov > bv || (ov == bv && oi < bi)){ bv = ov; bi = oi; }
        }
        if (ln < R + 1)
            out_rel[(size_t)c * B * (R+1) + (size_t)b * (R+1) + ln] = q;
        if (ln == 0){
            out_act[(size_t)(3*c) * B + b] = (float)bi;
            act_sh = bi;
        }
    }
    __syncthreads();
    // next step's gi (full-K): rel_gi[act] + gixc[b]
    const float* rg = rel_gi_c + (size_t)act_sh * H3;
    const float* gx = gixc_c + gbase;
    float* go = gi_next + gbase;
    #pragma unroll
    for (int u = 0; u < H3/256; ++u) go[t + 256*u] = rg[t + 256*u] + gx[t + 256*u];
}

// == fused copy step: combine(+splitK or full gi) + eos + u-dots + scores + softmax(101) + argmax + gather
__global__ __launch_bounds__(256) void k_copy_fused(
    const float* __restrict__ gi0, const float* __restrict__ gi1,
    const float* __restrict__ gh0, const float* __restrict__ gh1,
    int gi_full,
    const float* __restrict__ hold,
    const float* __restrict__ v,       // [B*S,100] = selu(enc)@Wf2^T
    const float* __restrict__ W_fuse, const float* __restrict__ b_fuse,
    const float* __restrict__ W_copy, const float* __restrict__ b_copy,
    const float* __restrict__ We, const float* __restrict__ be,
    const int* __restrict__ sentence, const float* __restrict__ word_emb,
    float* __restrict__ out_copy, int slot,
    float* __restrict__ emb, float* __restrict__ out_act, int aslot,
    float* __restrict__ hnew_out, const float* __restrict__ dec, int cell_end)
{
    __shared__ float hn[H];
    __shared__ float shl[H];
    __shared__ float u_lds[100];
    __shared__ float wc_lds[100];
    __shared__ float sco[101];
    __shared__ int   act_sh;
    const int b = blockIdx.x, t = threadIdx.x;
    const int wvi = t >> 6, ln = t & 63;
    const size_t gbase = (size_t)b * H3;
    for (int g = t; g < H; g += 256){
        float ir  = gi0[gbase + g];
        float iz  = gi0[gbase + H + g];
        float in_ = gi0[gbase + 2*H + g];
        if (!gi_full){
            ir  += gi1[gbase + g];
            iz  += gi1[gbase + H + g];
            in_ += gi1[gbase + 2*H + g];
        }
        const float hr  = gh0[gbase + g]       + gh1[gbase + g];
        const float hz  = gh0[gbase + H + g]   + gh1[gbase + H + g];
        const float hnn = gh0[gbase + 2*H + g] + gh1[gbase + 2*H + g];
        const float r = 1.f / (1.f + expf(-(ir + hr)));
        const float z = 1.f / (1.f + expf(-(iz + hz)));
        const float n = tanhf(in_ + r * hnn);
        const float hv = (1.f - z) * n + z * hold[(size_t)b * H + g];
        hn[g] = hv;
        shl[g] = selu_f(hv);
        hnew_out[(size_t)b * H + g] = cell_end ? 0.5f * (dec[(size_t)b * H + g] + hv) : hv;
    }
    if (t < 100) wc_lds[t] = W_copy[t];
    __syncthreads();
    for (int n = wvi; n < 100; n += 4){
        const float* wr = W_fuse + (size_t)n * (2*H);
        float a = 0.f;
        #pragma unroll
        for (int u = 0; u < H/64; ++u) a += shl[ln + 64*u] * wr[ln + 64*u];
        a = wred_sum(a);
        if (ln == 0) u_lds[n] = a + b_fuse[n];
    }
    if (wvi == 3){
        float a = 0.f;
        #pragma unroll
        for (int u = 0; u < H/64; ++u) a += hn[ln + 64*u] * We[ln + 64*u];
        a = wred_sum(a);
        if (ln == 0) sco[100] = a + be[0];
    }
    __syncthreads();
    const float bc = b_copy[0];
    for (int s = wvi; s < S; s += 4){
        const float* vb = v + ((size_t)b * S + s) * 100;
        float a = selu_f(u_lds[ln] + vb[ln]) * wc_lds[ln];
        if (ln + 64 < 100) a += selu_f(u_lds[ln + 64] + vb[ln + 64]) * wc_lds[ln + 64];
        a = wred_sum(a);
        if (ln == 0) sco[s] = a + bc;
    }
    __syncthreads();
    if (wvi == 0){
        const float v1 = sco[ln];
        const int i2 = ln + 64;
        const float v2 = (i2 <= S) ? sco[i2] : -INFINITY;
        const float m = wred_maxf(fmaxf(v1, v2));
        const float p1 = v1 - m, p2 = v2 - m;
        float e = expf(p1) + ((i2 <= S) ? expf(p2) : 0.f);
        const float lse = logf(wred_sum(e));
        const float q1 = p1 - lse, q2 = p2 - lse;
        float bv; int bi;
        if (q2 > q1){ bv = q2; bi = i2; } else { bv = q1; bi = ln; }
        #pragma unroll
        for (int o = 32; o > 0; o >>= 1){
            float ov = __shfl_xor(bv, o);
            int   oi = __shfl_xor(bi, o);
            if (ov > bv || (ov == bv && oi < bi)){ bv = ov; bi = oi; }
        }
        const size_t obase = (size_t)slot * B * (S+1) + (size_t)b * (S+1);
        out_copy[obase + ln] = q1;
        if (i2 <= S) out_copy[obase + i2] = q2;
        if (ln == 0){
            out_act[(size_t)aslot * B + b] = (float)bi;
            act_sh = bi;
        }
    }
    __syncthreads();
    const int act = act_sh;
    const int wd = sentence[b * S + (act < S ? act : S - 1)];
    const float* wr = word_emb + (size_t)wd * E;
    float* ebp = emb + (size_t)b * E;
    ebp[t] = wr[t];
    ebp[t + 256] = wr[t + 256];
}

extern "C" void kernel_launch(void* const* d_in, const int* in_sizes, int n_in,
                              void* d_out, int out_size, void* d_ws, size_t ws_size,
                              hipStream_t stream)
{
    (void)in_sizes; (void)n_in; (void)out_size; (void)ws_size;
    const int*   sentence = (const int*)  d_in[0];
    const float* dec      = (const float*)d_in[1];
    const float* enc      = (const float*)d_in[2];
    const float* word_emb = (const float*)d_in[3];
    const float* rel_emb  = (const float*)d_in[4];
    const float* sos      = (const float*)d_in[5];
    const float* W_comb   = (const float*)d_in[6];
    const float* b_comb   = (const float*)d_in[7];
    const float* W_attn   = (const float*)d_in[8];
    // d_in[9] = b_attn (cancels in softmax)
    const float* W_ih     = (const float*)d_in[10];
    const float* W_hh     = (const float*)d_in[11];
    const float* b_ih     = (const float*)d_in[12];
    const float* b_hh     = (const float*)d_in[13];
    const float* W_eos    = (const float*)d_in[14];
    const float* b_eos    = (const float*)d_in[15];
    const float* W_pred   = (const float*)d_in[16];
    const float* b_pred   = (const float*)d_in[17];
    const float* W_fuse   = (const float*)d_in[18];
    const float* b_fuse   = (const float*)d_in[19];
    const float* W_copy   = (const float*)d_in[20];
    const float* b_copy   = (const float*)d_in[21];

    float* out       = (float*)d_out;
    float* out_rel   = out;
    float* out_copy  = out + (size_t)NC * B * (R + 1);
    float* out_act   = out_copy + (size_t)2 * NC * B * (S + 1);

    float* p = (float*)d_ws;
    float* v_buf  = p; p += (size_t)B * S * 100;       // 2.56M
    float* Wihc   = p; p += (size_t)NC * H3 * E;       // 3.93M
    float* gixc   = p; p += (size_t)NC * B * H3;       // 1.97M
    float* rel_gi = p; p += (size_t)NC * 64 * H3;      // 0.49M
    float* Wc1T   = p; p += (size_t)E * E;             // 0.26M
    float* ctx    = p; p += B * H;
    float* xc     = p; p += B * E;
    float* emb    = p; p += B * E;
    float* hb0    = p; p += B * H;
    float* hb1    = p; p += B * H;
    float* gi0    = p; p += (size_t)B * H3;
    float* gi1    = p; p += (size_t)B * H3;
    float* gh0    = p; p += (size_t)B * H3;
    float* gh1    = p; p += (size_t)B * H3;
    float* hb[2]  = { hb0, hb1 };

    // ---- one-time precompute ----
    k_init<<<(B*E)/256, 256, 0, stream>>>(sos, dec, emb, hb0);
    k_ctx<<<B, 256, 0, stream>>>(enc, W_attn, ctx);
    // xc = ctx @ Wc2^T + b_comb
    k_gemm<<<dim3(4, 8, 1), 256, 0, stream>>>(
        ctx, H, 0, B, W_comb + E, H + E, 0, b_comb, 0,
        nullptr, 0, 0, xc, E, 0, E, H, 0);
    // Wc1^T
    k_transpose<<<dim3(8, 8), 256, 0, stream>>>(W_comb, Wc1T);
    // Wihc[c] = W_ih[c] @ Wc1   (batched z=5)
    k_gemm<<<dim3(4, H3/32, NC), 256, 0, stream>>>(
        W_ih, E, (long long)H3 * E, H3, Wc1T, E, 0, nullptr, 0,
        nullptr, 0, 0, Wihc, E, (long long)H3 * E, E, E, 0);
    // gixc[c] = xc @ W_ih[c]^T + b_ih[c]   (batched z=5)
    k_gemm<<<dim3(H3/128, 8, NC), 256, 0, stream>>>(
        xc, E, 0, B, W_ih, E, (long long)H3 * E, b_ih, H3,
        nullptr, 0, 0, gixc, H3, (long long)B * H3, H3, E, 0);
    // rel_gi[c] = rel_emb @ Wihc[c]^T   (M=51, batched z=5)
    k_gemm<<<dim3(H3/128, 2, NC), 256, 0, stream>>>(
        rel_emb, E, 0, R + 1, Wihc, E, (long long)H3 * E, nullptr, 0,
        nullptr, 0, 0, rel_gi, H3, (long long)64 * H3, H3, E, 0);
    // v = selu(enc) @ Wf2^T
    k_gemm<<<dim3(1, (B*S)/32, 1), 256, 0, stream>>>(
        enc, H, 0, B*S, W_fuse + H, 2*H, 0, nullptr, 0,
        nullptr, 0, 0, v_buf, 100, 0, 100, H, 1);

    int cur = 0;
    for (int c = 0; c < NC; ++c){
        const float* Wihc_c = Wihc + (size_t)c * H3 * E;
        const float* Whh_c  = W_hh + (size_t)c * H3 * H;
        const float* gixc_c = gixc + (size_t)c * B * H3;
        const float* bhh_c  = b_hh + (size_t)c * H3;
        for (int t3 = 0; t3 < 3; ++t3){
            const int giOn = (t3 != 1);
            k_gru2<<<dim3(giOn ? 24 : 12, 8, 2), 256, 0, stream>>>(
                emb, hb[cur], Wihc_c, Whh_c, gixc_c, bhh_c,
                gi0, gi1, gh0, gh1, giOn);
            if (t3 == 0){
                k_rel_fused<<<B, 256, 0, stream>>>(
                    gi0, gi1, gh0, gh1, hb[cur], W_pred, b_pred, W_eos, b_eos,
                    rel_gi + (size_t)c * 64 * H3, gixc_c, gi0,
                    out_rel, c, out_act, hb[cur^1]);
            } else {
                k_copy_fused<<<B, 256, 0, stream>>>(
                    gi0, gi1, gh0, gh1, (t3 == 1) ? 1 : 0, hb[cur], v_buf,
                    W_fuse, b_fuse, W_copy, b_copy, W_eos, b_eos,
                    sentence, word_emb,
                    out_copy, 2*c + (t3-1), emb, out_act, 3*c + t3,
                    hb[cur^1], dec, (t3 == 2) ? 1 : 0);
            }
            cur ^= 1;
        }
    }
}

// Round 10
// 1346.239 us; speedup vs baseline: 1.0640x; 1.0640x over previous
//
#include <hip/hip_runtime.h>
#include <math.h>

#define B 256
#define S 100
#define H 512
#define E 512
#define R 50
#define NC 5
#define H3 1536
#define KSPLIT 4

__device__ __forceinline__ float selu_f(float x){
    return x > 0.0f ? 1.0507009873554805f * x
                    : 1.7580993408473766f * expm1f(x);   // scale*alpha
}
__device__ __forceinline__ float wred_sum(float v){
    #pragma unroll
    for (int o = 32; o > 0; o >>= 1) v += __shfl_xor(v, o);
    return v;
}
__device__ __forceinline__ float wred_maxf(float v){
    #pragma unroll
    for (int o = 32; o > 0; o >>= 1) v = fmaxf(v, __shfl_xor(v, o));
    return v;
}

// ============== 64x128 tiled f32 GEMM, 4x8/thread, conflict-free col map ==============
// per-thread cols {tx*4..+3, 64+tx*4..+3}: Ws read stride 16B/lane -> 2-way conflict (free)
// per kk: 32 FMA vs 3 ds_read_b128 -> VALU-bound
struct GSmem {
    alignas(16) float As[16][68];    // [k][m]
    alignas(16) float Ws[16][132];   // [k][n]
};

__device__ __forceinline__ void gemm64(
    GSmem& sm,
    const float* __restrict__ A, int lda, int M,
    const float* __restrict__ W, int ldw,
    const float* __restrict__ bias,
    const float* __restrict__ addm, int ldadd,
    float* __restrict__ C, int ldc,
    int N, int m0, int n0, int k0beg, int k0end, int seluA)
{
    const int t  = threadIdx.x;
    const int tx = t & 15;            // n-group
    const int ty = t >> 4;            // m-group (4 rows)
    const int lm = t >> 2,  lk  = (t & 3) << 2;   // A loader: float4
    const int lw = t >> 1,  lkw = (t & 1) << 3;   // W loader: 2x float4
    int am = m0 + lm; if (am >= M) am = M - 1;    // row clamp
    const float* Ap = A + (size_t)am * lda + lk;
    const int nw = n0 + lw;
    const float* Wp = W + (size_t)nw * ldw + lkw;
    const bool wok = (nw < N);
    const float4 f40 = make_float4(0.f, 0.f, 0.f, 0.f);

    float4 ar = *(const float4*)(Ap + k0beg);
    if (seluA){ ar.x = selu_f(ar.x); ar.y = selu_f(ar.y); ar.z = selu_f(ar.z); ar.w = selu_f(ar.w); }
    float4 w0 = wok ? *(const float4*)(Wp + k0beg)     : f40;
    float4 w1 = wok ? *(const float4*)(Wp + k0beg + 4) : f40;

    float acc[4][8] = {};
    for (int k0 = k0beg; k0 < k0end; k0 += 16){
        if (k0 != k0beg) __syncthreads();
        sm.As[lk+0][lm] = ar.x; sm.As[lk+1][lm] = ar.y;
        sm.As[lk+2][lm] = ar.z; sm.As[lk+3][lm] = ar.w;
        sm.Ws[lkw+0][lw] = w0.x; sm.Ws[lkw+1][lw] = w0.y;
        sm.Ws[lkw+2][lw] = w0.z; sm.Ws[lkw+3][lw] = w0.w;
        sm.Ws[lkw+4][lw] = w1.x; sm.Ws[lkw+5][lw] = w1.y;
        sm.Ws[lkw+6][lw] = w1.z; sm.Ws[lkw+7][lw] = w1.w;
        __syncthreads();
        if (k0 + 16 < k0end){
            ar = *(const float4*)(Ap + k0 + 16);
            if (seluA){ ar.x = selu_f(ar.x); ar.y = selu_f(ar.y); ar.z = selu_f(ar.z); ar.w = selu_f(ar.w); }
            w0 = wok ? *(const float4*)(Wp + k0 + 16)     : f40;
            w1 = wok ? *(const float4*)(Wp + k0 + 16 + 4) : f40;
        }
        #pragma unroll
        for (int kk = 0; kk < 16; ++kk){
            const float4 av  = *(const float4*)&sm.As[kk][ty*4];     // broadcast across tx
            const float4 wv0 = *(const float4*)&sm.Ws[kk][tx*4];     // 2-way
            const float4 wv1 = *(const float4*)&sm.Ws[kk][tx*4 + 64];
            const float aa[4] = {av.x, av.y, av.z, av.w};
            const float bb[8] = {wv0.x, wv0.y, wv0.z, wv0.w, wv1.x, wv1.y, wv1.z, wv1.w};
            #pragma unroll
            for (int i = 0; i < 4; ++i)
                #pragma unroll
                for (int j = 0; j < 8; ++j)
                    acc[i][j] += aa[i] * bb[j];
        }
    }
    #pragma unroll
    for (int i = 0; i < 4; ++i){
        const int m = m0 + ty*4 + i;
        if (m < M){
            #pragma unroll
            for (int j = 0; j < 8; ++j){
                const int n = n0 + ((j < 4) ? (tx*4 + j) : (64 + tx*4 + j - 4));
                if (n < N){
                    float vv = acc[i][j];
                    if (bias) vv += bias[n];
                    if (addm) vv += addm[(size_t)m * ldadd + n];
                    C[(size_t)m * ldc + n] = vv;
                }
            }
        }
    }
}

// generic batched GEMM: grid (ceil(N/128), ceil(M/64), batch)
__global__ __launch_bounds__(256) void k_gemm(
    const float* A, int lda, long long sA, int M,
    const float* W, int ldw, long long sW,
    const float* bias, long long sBias,
    const float* addm, int ldadd, long long sAddm,
    float* C, int ldc, long long sC,
    int N, int K, int seluA)
{
    __shared__ GSmem sm;
    const int z = blockIdx.z;
    gemm64(sm,
           A + (size_t)z * sA, lda, M,
           W + (size_t)z * sW, ldw,
           bias ? bias + (size_t)z * sBias : nullptr,
           addm ? addm + (size_t)z * sAddm : nullptr, ldadd,
           C + (size_t)z * sC, ldc,
           N, blockIdx.y * 64, blockIdx.x * 128, 0, K, seluA);
}

// per-step GEMM, split-K=4.
// giOn=1: grid (24, 4, 4): x<12 gi tiles, x>=12 gh tiles.  giOn=0: grid (12, 4, 4): gh only.
__global__ __launch_bounds__(256) void k_gru2(
    const float* emb, const float* h,
    const float* Wihc, const float* Whh,
    const float* gixc, const float* bhh,
    float* gip, float* ghp, int giOn)     // gip/ghp: [KSPLIT][B][H3]
{
    __shared__ GSmem sm;
    int xt = blockIdx.x;
    const int m0 = blockIdx.y * 64;
    const int z  = blockIdx.z;
    const int kb = z * (H / KSPLIT), ke = kb + (H / KSPLIT);
    if (giOn && xt < 12){
        gemm64(sm, emb, E, B, Wihc, E, nullptr,
               (z == 0) ? gixc : nullptr, H3,
               gip + (size_t)z * B * H3, H3,
               H3, m0, xt * 128, kb, ke, 0);
    } else {
        if (giOn) xt -= 12;
        gemm64(sm, h, H, B, Whh, H,
               (z == 0) ? bhh : nullptr, nullptr, 0,
               ghp + (size_t)z * B * H3, H3,
               H3, m0, xt * 128, kb, ke, 0);
    }
}

// ================= attention context (loop-invariant) =================
__global__ __launch_bounds__(256) void k_ctx(const float* __restrict__ enc,
                                             const float* __restrict__ W_attn,
                                             float* __restrict__ ctx)
{
    __shared__ float sc[128];
    __shared__ float red[128];
    const int b = blockIdx.x;
    const int t = threadIdx.x;
    const int wv = t >> 6, ln = t & 63;
    const float* eb = enc + (size_t)b * S * H;
    const float* wa = W_attn + H;
    for (int s = wv; s < S; s += 4){
        const float* es = eb + (size_t)s * H;
        float a = 0.f;
        #pragma unroll
        for (int u = 0; u < H/64; ++u) a += es[ln + 64*u] * wa[ln + 64*u];
        a = wred_sum(a);
        if (ln == 0) sc[s] = a;
    }
    __syncthreads();
    float vm = (t < S) ? sc[t] : -INFINITY;
    if (t < 128) red[t] = vm;
    __syncthreads();
    for (int st = 64; st > 0; st >>= 1){
        if (t < st) red[t] = fmaxf(red[t], red[t + st]);
        __syncthreads();
    }
    const float m = red[0];
    __syncthreads();
    float e = (t < S) ? expf(sc[t] - m) : 0.f;
    if (t < 128) red[t] = e;
    __syncthreads();
    for (int st = 64; st > 0; st >>= 1){
        if (t < st) red[t] += red[t + st];
        __syncthreads();
    }
    const float sum = red[0];
    __syncthreads();
    if (t < S) sc[t] = e / sum;
    __syncthreads();
    for (int hh = t; hh < H; hh += 256){
        float a = 0.f;
        for (int s = 0; s < S; ++s) a += sc[s] * eb[(size_t)s * H + hh];
        ctx[(size_t)b * H + hh] = a;
    }
}

// ================= Wc1^T (for the Wihc fold) =================
__global__ __launch_bounds__(256) void k_transpose(const float* __restrict__ Wc,
                                                   float* __restrict__ WT)
{
    __shared__ float tile[64][65];
    const int bx = blockIdx.x * 64;   // k range
    const int by = blockIdx.y * 64;   // j range
    const int t = threadIdx.x;
    const int c4 = (t & 15) * 4, rg = t >> 4;
    for (int r = 0; r < 64; r += 16){
        float4 v = *(const float4*)(Wc + (size_t)(by + rg + r) * (H + E) + bx + c4);
        tile[rg + r][c4+0] = v.x; tile[rg + r][c4+1] = v.y;
        tile[rg + r][c4+2] = v.z; tile[rg + r][c4+3] = v.w;
    }
    __syncthreads();
    for (int r = 0; r < 64; r += 16){
        WT[(size_t)(bx + rg + r) * E + by + c4 + 0] = tile[c4+0][rg + r];
        WT[(size_t)(bx + rg + r) * E + by + c4 + 1] = tile[c4+1][rg + r];
        WT[(size_t)(bx + rg + r) * E + by + c4 + 2] = tile[c4+2][rg + r];
        WT[(size_t)(bx + rg + r) * E + by + c4 + 3] = tile[c4+3][rg + r];
    }
}

// ================= init: emb = sos, h0 = 0.5*dec =================
__global__ __launch_bounds__(256) void k_init(
    const float* __restrict__ sos, const float* __restrict__ dec,
    float* __restrict__ emb, float* __restrict__ h0)
{
    const int idx = blockIdx.x * 256 + threadIdx.x;
    emb[idx] = sos[idx & (E - 1)];
    h0[idx]  = 0.5f * dec[idx];
}

// ====== fused rel step: combine(splitK=4) + 51 logits + softmax + argmax + NEXT-gi write ======
__global__ __launch_bounds__(256) void k_rel_fused(
    const float* __restrict__ gip, const float* __restrict__ ghp,
    const float* __restrict__ hold,
    const float* __restrict__ Wp, const float* __restrict__ bp,
    const float* __restrict__ We, const float* __restrict__ be,
    const float* __restrict__ rel_gi_c,    // [64, H3] precomputed rel_emb @ Wihc^T
    const float* __restrict__ gixc_c,      // [B, H3]
    float* __restrict__ gi_next,           // gip[0]: full-K gi for next step
    float* __restrict__ out_rel, int c,
    float* __restrict__ out_act,
    float* __restrict__ hnew_out)
{
    __shared__ float hn[H];
    __shared__ float logits[R + 1];
    __shared__ int   act_sh;
    const int b = blockIdx.x, t = threadIdx.x;
    const int wvi = t >> 6, ln = t & 63;
    const size_t gbase = (size_t)b * H3;
    for (int g = t; g < H; g += 256){
        float ir = 0.f, hr = 0.f, iz = 0.f, hz = 0.f, in_ = 0.f, hnn = 0.f;
        #pragma unroll
        for (int z = 0; z < KSPLIT; ++z){
            const size_t o = (size_t)z * B * H3 + gbase;
            ir  += gip[o + g];        hr  += ghp[o + g];
            iz  += gip[o + H + g];    hz  += ghp[o + H + g];
            in_ += gip[o + 2*H + g];  hnn += ghp[o + 2*H + g];
        }
        const float r = 1.f / (1.f + expf(-(ir + hr)));
        const float z = 1.f / (1.f + expf(-(iz + hz)));
        const float n = tanhf(in_ + r * hnn);
        const float hv = (1.f - z) * n + z * hold[(size_t)b * H + g];
        hn[g] = hv;
        hnew_out[(size_t)b * H + g] = hv;
    }
    __syncthreads();
    for (int i = wvi; i < R + 1; i += 4){
        const float* wr = (i < R) ? Wp + (size_t)i * H : We;
        float a = 0.f;
        #pragma unroll
        for (int u = 0; u < H/64; ++u) a += hn[ln + 64*u] * wr[ln + 64*u];
        a = wred_sum(a);
        if (ln == 0) logits[i] = a + (i < R ? bp[i] : be[0]);
    }
    __syncthreads();
    if (wvi == 0){
        const float v = (ln < R + 1) ? logits[ln] : -INFINITY;
        const float m = wred_maxf(v);
        const float p = v - m;
        const float e = (ln < R + 1) ? expf(p) : 0.f;
        const float lse = logf(wred_sum(e));
        const float q = p - lse;
        float bv = q; int bi = ln;
        #pragma unroll
        for (int o = 32; o > 0; o >>= 1){
            float ov = __shfl_xor(bv, o);
            int   oi = __shfl_xor(bi, o);
            if (ov > bv || (ov == bv && oi < bi)){ bv = ov; bi = oi; }
        }
        if (ln < R + 1)
            out_rel[(size_t)c * B * (R+1) + (size_t)b * (R+1) + ln] = q;
        if (ln == 0){
            out_act[(size_t)(3*c) * B + b] = (float)bi;
            act_sh = bi;
        }
    }
    __syncthreads();
    // next step's gi (full-K): rel_gi[act] + gixc[b]
    const float* rg = rel_gi_c + (size_t)act_sh * H3;
    const float* gx = gixc_c + gbase;
    float* go = gi_next + gbase;
    #pragma unroll
    for (int u = 0; u < H3/256; ++u) go[t + 256*u] = rg[t + 256*u] + gx[t + 256*u];
}

// == fused copy step: combine(splitK or full gi) + eos + u-dots + scores + softmax(101) + argmax + gather
__global__ __launch_bounds__(256) void k_copy_fused(
    const float* __restrict__ gip, const float* __restrict__ ghp,
    int gi_full,
    const float* __restrict__ hold,
    const float* __restrict__ v,       // [B*S,100] = selu(enc)@Wf2^T
    const float* __restrict__ W_fuse, const float* __restrict__ b_fuse,
    const float* __restrict__ W_copy, const float* __restrict__ b_copy,
    const float* __restrict__ We, const float* __restrict__ be,
    const int* __restrict__ sentence, const float* __restrict__ word_emb,
    float* __restrict__ out_copy, int slot,
    float* __restrict__ emb, float* __restrict__ out_act, int aslot,
    float* __restrict__ hnew_out, const float* __restrict__ dec, int cell_end)
{
    __shared__ float hn[H];
    __shared__ float shl[H];
    __shared__ float u_lds[100];
    __shared__ float wc_lds[100];
    __shared__ float sco[101];
    __shared__ int   act_sh;
    const int b = blockIdx.x, t = threadIdx.x;
    const int wvi = t >> 6, ln = t & 63;
    const size_t gbase = (size_t)b * H3;
    for (int g = t; g < H; g += 256){
        float ir, iz, in_;
        if (gi_full){
            ir  = gip[gbase + g];
            iz  = gip[gbase + H + g];
            in_ = gip[gbase + 2*H + g];
        } else {
            ir = 0.f; iz = 0.f; in_ = 0.f;
            #pragma unroll
            for (int z = 0; z < KSPLIT; ++z){
                const size_t o = (size_t)z * B * H3 + gbase;
                ir += gip[o + g]; iz += gip[o + H + g]; in_ += gip[o + 2*H + g];
            }
        }
        float hr = 0.f, hz = 0.f, hnn = 0.f;
        #pragma unroll
        for (int z = 0; z < KSPLIT; ++z){
            const size_t o = (size_t)z * B * H3 + gbase;
            hr += ghp[o + g]; hz += ghp[o + H + g]; hnn += ghp[o + 2*H + g];
        }
        const float r = 1.f / (1.f + expf(-(ir + hr)));
        const float z = 1.f / (1.f + expf(-(iz + hz)));
        const float n = tanhf(in_ + r * hnn);
        const float hv = (1.f - z) * n + z * hold[(size_t)b * H + g];
        hn[g] = hv;
        shl[g] = selu_f(hv);
        hnew_out[(size_t)b * H + g] = cell_end ? 0.5f * (dec[(size_t)b * H + g] + hv) : hv;
    }
    if (t < 100) wc_lds[t] = W_copy[t];
    __syncthreads();
    for (int n = wvi; n < 100; n += 4){
        const float* wr = W_fuse + (size_t)n * (2*H);
        float a = 0.f;
        #pragma unroll
        for (int u = 0; u < H/64; ++u) a += shl[ln + 64*u] * wr[ln + 64*u];
        a = wred_sum(a);
        if (ln == 0) u_lds[n] = a + b_fuse[n];
    }
    if (wvi == 3){
        float a = 0.f;
        #pragma unroll
        for (int u = 0; u < H/64; ++u) a += hn[ln + 64*u] * We[ln + 64*u];
        a = wred_sum(a);
        if (ln == 0) sco[100] = a + be[0];
    }
    __syncthreads();
    const float bc = b_copy[0];
    for (int s = wvi; s < S; s += 4){
        const float* vb = v + ((size_t)b * S + s) * 100;
        float a = selu_f(u_lds[ln] + vb[ln]) * wc_lds[ln];
        if (ln + 64 < 100) a += selu_f(u_lds[ln + 64] + vb[ln + 64]) * wc_lds[ln + 64];
        a = wred_sum(a);
        if (ln == 0) sco[s] = a + bc;
    }
    __syncthreads();
    if (wvi == 0){
        const float v1 = sco[ln];
        const int i2 = ln + 64;
        const float v2 = (i2 <= S) ? sco[i2] : -INFINITY;
        const float m = wred_maxf(fmaxf(v1, v2));
        const float p1 = v1 - m, p2 = v2 - m;
        float e = expf(p1) + ((i2 <= S) ? expf(p2) : 0.f);
        const float lse = logf(wred_sum(e));
        const float q1 = p1 - lse, q2 = p2 - lse;
        float bv; int bi;
        if (q2 > q1){ bv = q2; bi = i2; } else { bv = q1; bi = ln; }
        #pragma unroll
        for (int o = 32; o > 0; o >>= 1){
            float ov = __shfl_xor(bv, o);
            int   oi = __shfl_xor(bi, o);
            if (ov > bv || (ov == bv && oi < bi)){ bv = ov; bi = oi; }
        }
        const size_t obase = (size_t)slot * B * (S+1) + (size_t)b * (S+1);
        out_copy[obase + ln] = q1;
        if (i2 <= S) out_copy[obase + i2] = q2;
        if (ln == 0){
            out_act[(size_t)aslot * B + b] = (float)bi;
            act_sh = bi;
        }
    }
    __syncthreads();
    const int act = act_sh;
    const int wd = sentence[b * S + (act < S ? act : S - 1)];
    const float* wr = word_emb + (size_t)wd * E;
    float* ebp = emb + (size_t)b * E;
    ebp[t] = wr[t];
    ebp[t + 256] = wr[t + 256];
}

extern "C" void kernel_launch(void* const* d_in, const int* in_sizes, int n_in,
                              void* d_out, int out_size, void* d_ws, size_t ws_size,
                              hipStream_t stream)
{
    (void)in_sizes; (void)n_in; (void)out_size; (void)ws_size;
    const int*   sentence = (const int*)  d_in[0];
    const float* dec      = (const float*)d_in[1];
    const float* enc      = (const float*)d_in[2];
    const float* word_emb = (const float*)d_in[3];
    const float* rel_emb  = (const float*)d_in[4];
    const float* sos      = (const float*)d_in[5];
    const float* W_comb   = (const float*)d_in[6];
    const float* b_comb   = (const float*)d_in[7];
    const float* W_attn   = (const float*)d_in[8];
    // d_in[9] = b_attn (cancels in softmax)
    const float* W_ih     = (const float*)d_in[10];
    const float* W_hh     = (const float*)d_in[11];
    const float* b_ih     = (const float*)d_in[12];
    const float* b_hh     = (const float*)d_in[13];
    const float* W_eos    = (const float*)d_in[14];
    const float* b_eos    = (const float*)d_in[15];
    const float* W_pred   = (const float*)d_in[16];
    const float* b_pred   = (const float*)d_in[17];
    const float* W_fuse   = (const float*)d_in[18];
    const float* b_fuse   = (const float*)d_in[19];
    const float* W_copy   = (const float*)d_in[20];
    const float* b_copy   = (const float*)d_in[21];

    float* out       = (float*)d_out;
    float* out_rel   = out;
    float* out_copy  = out + (size_t)NC * B * (R + 1);
    float* out_act   = out_copy + (size_t)2 * NC * B * (S + 1);

    float* p = (float*)d_ws;
    float* v_buf  = p; p += (size_t)B * S * 100;        // 2.56M
    float* Wihc   = p; p += (size_t)NC * H3 * E;        // 3.93M
    float* gixc   = p; p += (size_t)NC * B * H3;        // 1.97M
    float* rel_gi = p; p += (size_t)NC * 64 * H3;       // 0.49M
    float* Wc1T   = p; p += (size_t)E * E;              // 0.26M
    float* ctx    = p; p += B * H;
    float* xc     = p; p += B * E;
    float* emb    = p; p += B * E;
    float* hb0    = p; p += B * H;
    float* hb1    = p; p += B * H;
    float* gip    = p; p += (size_t)KSPLIT * B * H3;    // 1.57M
    float* ghp    = p; p += (size_t)KSPLIT * B * H3;    // 1.57M
    float* hb[2]  = { hb0, hb1 };

    // ---- one-time precompute ----
    k_init<<<(B*E)/256, 256, 0, stream>>>(sos, dec, emb, hb0);
    k_ctx<<<B, 256, 0, stream>>>(enc, W_attn, ctx);
    // xc = ctx @ Wc2^T + b_comb
    k_gemm<<<dim3(4, 4, 1), 256, 0, stream>>>(
        ctx, H, 0, B, W_comb + E, H + E, 0, b_comb, 0,
        nullptr, 0, 0, xc, E, 0, E, H, 0);
    // Wc1^T
    k_transpose<<<dim3(8, 8), 256, 0, stream>>>(W_comb, Wc1T);
    // Wihc[c] = W_ih[c] @ Wc1   (batched z=5)
    k_gemm<<<dim3(4, H3/64, NC), 256, 0, stream>>>(
        W_ih, E, (long long)H3 * E, H3, Wc1T, E, 0, nullptr, 0,
        nullptr, 0, 0, Wihc, E, (long long)H3 * E, E, E, 0);
    // gixc[c] = xc @ W_ih[c]^T + b_ih[c]   (batched z=5)
    k_gemm<<<dim3(H3/128, 4, NC), 256, 0, stream>>>(
        xc, E, 0, B, W_ih, E, (long long)H3 * E, b_ih, H3,
        nullptr, 0, 0, gixc, H3, (long long)B * H3, H3, E, 0);
    // rel_gi[c] = rel_emb @ Wihc[c]^T   (M=51, batched z=5)
    k_gemm<<<dim3(H3/128, 1, NC), 256, 0, stream>>>(
        rel_emb, E, 0, R + 1, Wihc, E, (long long)H3 * E, nullptr, 0,
        nullptr, 0, 0, rel_gi, H3, (long long)64 * H3, H3, E, 0);
    // v = selu(enc) @ Wf2^T
    k_gemm<<<dim3(1, (B*S)/64, 1), 256, 0, stream>>>(
        enc, H, 0, B*S, W_fuse + H, 2*H, 0, nullptr, 0,
        nullptr, 0, 0, v_buf, 100, 0, 100, H, 1);

    int cur = 0;
    for (int c = 0; c < NC; ++c){
        const float* Wihc_c = Wihc + (size_t)c * H3 * E;
        const float* Whh_c  = W_hh + (size_t)c * H3 * H;
        const float* gixc_c = gixc + (size_t)c * B * H3;
        const float* bhh_c  = b_hh + (size_t)c * H3;
        for (int t3 = 0; t3 < 3; ++t3){
            const int giOn = (t3 != 1);
            k_gru2<<<dim3(giOn ? 24 : 12, 4, KSPLIT), 256, 0, stream>>>(
                emb, hb[cur], Wihc_c, Whh_c, gixc_c, bhh_c,
                gip, ghp, giOn);
            if (t3 == 0){
                k_rel_fused<<<B, 256, 0, stream>>>(
                    gip, ghp, hb[cur], W_pred, b_pred, W_eos, b_eos,
                    rel_gi + (size_t)c * 64 * H3, gixc_c, gip,
                    out_rel, c, out_act, hb[cur^1]);
            } else {
                k_copy_fused<<<B, 256, 0, stream>>>(
                    gip, ghp, (t3 == 1) ? 1 : 0, hb[cur], v_buf,
                    W_fuse, b_fuse, W_copy, b_copy, W_eos, b_eos,
                    sentence, word_emb,
                    out_copy, 2*c + (t3-1), emb, out_act, 3*c + t3,
                    hb[cur^1], dec, (t3 == 2) ? 1 : 0);
            }
            cur ^= 1;
        }
    }
}

// Round 11
// 1244.296 us; speedup vs baseline: 1.1511x; 1.0819x over previous
//
#include <hip/hip_runtime.h>
#include <math.h>

#define B 256
#define S 100
#define H 512
#define E 512
#define R 50
#define NC 5
#define H3 1536

__device__ __forceinline__ float selu_f(float x){
    return x > 0.0f ? 1.0507009873554805f * x
                    : 1.7580993408473766f * expm1f(x);   // scale*alpha
}
__device__ __forceinline__ float wred_sum(float v){
    #pragma unroll
    for (int o = 32; o > 0; o >>= 1) v += __shfl_xor(v, o);
    return v;
}
__device__ __forceinline__ float wred_maxf(float v){
    #pragma unroll
    for (int o = 32; o > 0; o >>= 1) v = fmaxf(v, __shfl_xor(v, o));
    return v;
}

// ============== 64x128 tiled f32 GEMM, 4x8/thread, conflict-free col map ==============
struct GSmem {
    alignas(16) float As[16][68];    // [k][m]
    alignas(16) float Ws[16][132];   // [k][n]
};

__device__ __forceinline__ void gemm64(
    GSmem& sm,
    const float* __restrict__ A, int lda, int M,
    const float* __restrict__ W, int ldw,
    const float* __restrict__ bias,
    const float* __restrict__ addm, int ldadd,
    float* __restrict__ C, int ldc,
    int N, int m0, int n0, int k0beg, int k0end, int seluA)
{
    const int t  = threadIdx.x;
    const int tx = t & 15;
    const int ty = t >> 4;
    const int lm = t >> 2,  lk  = (t & 3) << 2;
    const int lw = t >> 1,  lkw = (t & 1) << 3;
    int am = m0 + lm; if (am >= M) am = M - 1;
    const float* Ap = A + (size_t)am * lda + lk;
    const int nw = n0 + lw;
    const float* Wp = W + (size_t)nw * ldw + lkw;
    const bool wok = (nw < N);
    const float4 f40 = make_float4(0.f, 0.f, 0.f, 0.f);

    float4 ar = *(const float4*)(Ap + k0beg);
    if (seluA){ ar.x = selu_f(ar.x); ar.y = selu_f(ar.y); ar.z = selu_f(ar.z); ar.w = selu_f(ar.w); }
    float4 w0 = wok ? *(const float4*)(Wp + k0beg)     : f40;
    float4 w1 = wok ? *(const float4*)(Wp + k0beg + 4) : f40;

    float acc[4][8] = {};
    for (int k0 = k0beg; k0 < k0end; k0 += 16){
        if (k0 != k0beg) __syncthreads();
        sm.As[lk+0][lm] = ar.x; sm.As[lk+1][lm] = ar.y;
        sm.As[lk+2][lm] = ar.z; sm.As[lk+3][lm] = ar.w;
        sm.Ws[lkw+0][lw] = w0.x; sm.Ws[lkw+1][lw] = w0.y;
        sm.Ws[lkw+2][lw] = w0.z; sm.Ws[lkw+3][lw] = w0.w;
        sm.Ws[lkw+4][lw] = w1.x; sm.Ws[lkw+5][lw] = w1.y;
        sm.Ws[lkw+6][lw] = w1.z; sm.Ws[lkw+7][lw] = w1.w;
        __syncthreads();
        if (k0 + 16 < k0end){
            ar = *(const float4*)(Ap + k0 + 16);
            if (seluA){ ar.x = selu_f(ar.x); ar.y = selu_f(ar.y); ar.z = selu_f(ar.z); ar.w = selu_f(ar.w); }
            w0 = wok ? *(const float4*)(Wp + k0 + 16)     : f40;
            w1 = wok ? *(const float4*)(Wp + k0 + 16 + 4) : f40;
        }
        #pragma unroll
        for (int kk = 0; kk < 16; ++kk){
            const float4 av  = *(const float4*)&sm.As[kk][ty*4];
            const float4 wv0 = *(const float4*)&sm.Ws[kk][tx*4];
            const float4 wv1 = *(const float4*)&sm.Ws[kk][tx*4 + 64];
            const float aa[4] = {av.x, av.y, av.z, av.w};
            const float bb[8] = {wv0.x, wv0.y, wv0.z, wv0.w, wv1.x, wv1.y, wv1.z, wv1.w};
            #pragma unroll
            for (int i = 0; i < 4; ++i)
                #pragma unroll
                for (int j = 0; j < 8; ++j)
                    acc[i][j] += aa[i] * bb[j];
        }
    }
    #pragma unroll
    for (int i = 0; i < 4; ++i){
        const int m = m0 + ty*4 + i;
        if (m < M){
            #pragma unroll
            for (int j = 0; j < 8; ++j){
                const int n = n0 + ((j < 4) ? (tx*4 + j) : (64 + tx*4 + j - 4));
                if (n < N){
                    float vv = acc[i][j];
                    if (bias) vv += bias[n];
                    if (addm) vv += addm[(size_t)m * ldadd + n];
                    C[(size_t)m * ldc + n] = vv;
                }
            }
        }
    }
}

// ================= multi-job GEMM (one launch fills the GPU) =================
struct GemmJob {
    const float* A; int lda; long long sA; int M;
    const float* W; int ldw; long long sW;
    const float* bias; long long sBias;
    const float* addm; int ldadd; long long sAddm;
    float* C; int ldc; long long sC;
    int N, K, seluA;
    int nx, ny, base;
};
struct Jobs4 { GemmJob j[4]; };

__global__ __launch_bounds__(256) void k_mgemm(Jobs4 js)
{
    __shared__ GSmem sm;
    const int bid = blockIdx.x;
    GemmJob j;
    if      (bid >= js.j[3].base) j = js.j[3];
    else if (bid >= js.j[2].base) j = js.j[2];
    else if (bid >= js.j[1].base) j = js.j[1];
    else                          j = js.j[0];
    const int local = bid - j.base;
    const int z = local / (j.nx * j.ny);
    const int r = local % (j.nx * j.ny);
    const int y = r / j.nx, x = r % j.nx;
    gemm64(sm,
           j.A + (size_t)z * j.sA, j.lda, j.M,
           j.W + (size_t)z * j.sW, j.ldw,
           j.bias ? j.bias + (size_t)z * j.sBias : nullptr,
           j.addm ? j.addm + (size_t)z * j.sAddm : nullptr, j.ldadd,
           j.C + (size_t)z * j.sC, j.ldc,
           j.N, y * 64, x * 128, 0, j.K, j.seluA);
}

// ================= P0: init + W_comb transpose + (ctx->xc fused) + rel_x GEMM =================
// blocks: [0,8) init | [8,136) transpose | [136,392) ctx+xc per-b | [392,396) rel_x
__global__ __launch_bounds__(256) void k_pre0(
    const float* __restrict__ sos, const float* __restrict__ dec,
    const float* __restrict__ enc, const float* __restrict__ W_attn,
    const float* __restrict__ W_comb, const float* __restrict__ b_comb,
    const float* __restrict__ rel_emb,
    float* __restrict__ emb, float* __restrict__ h0,
    float* __restrict__ WcT, float* __restrict__ xc,
    float* __restrict__ relx)
{
    __shared__ __align__(16) char smraw[16704];
    const int bid = blockIdx.x, t = threadIdx.x;
    if (bid < 8){
        for (int idx = bid * 256 + t; idx < B * E; idx += 8 * 256){
            emb[idx] = sos[idx & (E - 1)];
            h0[idx]  = 0.5f * dec[idx];
        }
    } else if (bid < 136){
        float (*tile)[65] = (float(*)[65])smraw;
        const int tt = bid - 8;
        const int bx = (tt & 15) * 64;   // col range of W_comb (1024)
        const int by = (tt >> 4) * 64;   // row range (512)
        const int c4 = (t & 15) * 4, rg = t >> 4;
        for (int rr = 0; rr < 64; rr += 16){
            float4 v = *(const float4*)(W_comb + (size_t)(by + rg + rr) * (H + E) + bx + c4);
            tile[rg + rr][c4+0] = v.x; tile[rg + rr][c4+1] = v.y;
            tile[rg + rr][c4+2] = v.z; tile[rg + rr][c4+3] = v.w;
        }
        __syncthreads();
        for (int rr = 0; rr < 64; rr += 16){
            WcT[(size_t)(bx + rg + rr) * E + by + c4 + 0] = tile[c4+0][rg + rr];
            WcT[(size_t)(bx + rg + rr) * E + by + c4 + 1] = tile[c4+1][rg + rr];
            WcT[(size_t)(bx + rg + rr) * E + by + c4 + 2] = tile[c4+2][rg + rr];
            WcT[(size_t)(bx + rg + rr) * E + by + c4 + 3] = tile[c4+3][rg + rr];
        }
    } else if (bid < 392){
        float* aw   = (float*)smraw;       // 128
        float* red  = aw + 128;            // 128
        float* ctxl = red + 128;           // 512
        const int b = bid - 136;
        const int wv = t >> 6, ln = t & 63;
        const float* eb = enc + (size_t)b * S * H;
        const float* wa = W_attn + H;
        for (int s = wv; s < S; s += 4){
            const float* es = eb + (size_t)s * H;
            float a = 0.f;
            #pragma unroll
            for (int u = 0; u < H/64; ++u) a += es[ln + 64*u] * wa[ln + 64*u];
            a = wred_sum(a);
            if (ln == 0) aw[s] = a;
        }
        __syncthreads();
        float vm = (t < S) ? aw[t] : -INFINITY;
        if (t < 128) red[t] = vm;
        __syncthreads();
        for (int st = 64; st > 0; st >>= 1){
            if (t < st) red[t] = fmaxf(red[t], red[t + st]);
            __syncthreads();
        }
        const float m = red[0];
        __syncthreads();
        float e = (t < S) ? expf(aw[t] - m) : 0.f;
        if (t < 128) red[t] = e;
        __syncthreads();
        for (int st = 64; st > 0; st >>= 1){
            if (t < st) red[t] += red[t + st];
            __syncthreads();
        }
        const float sum = red[0];
        __syncthreads();
        if (t < S) aw[t] = e / sum;
        __syncthreads();
        for (int hh = t; hh < H; hh += 256){
            float a = 0.f;
            for (int s = 0; s < S; ++s) a += aw[s] * eb[(size_t)s * H + hh];
            ctxl[hh] = a;
        }
        __syncthreads();
        // xc[b,n] = ctxl . Wc2[n,:] + b_comb[n]
        for (int n = wv; n < E; n += 4){
            const float* wr = W_comb + (size_t)n * (H + E) + E;
            float a = 0.f;
            #pragma unroll
            for (int u = 0; u < H/64; ++u) a += ctxl[ln + 64*u] * wr[ln + 64*u];
            a = wred_sum(a);
            if (ln == 0) xc[(size_t)b * E + n] = a + b_comb[n];
        }
    } else {
        GSmem& sm = *(GSmem*)smraw;
        // rel_x = rel_emb @ Wc1^T  (M=51, N=512, K=512); Wc1 rows = W_comb rows, ldw=H+E
        gemm64(sm, rel_emb, E, R + 1, W_comb, H + E, nullptr, nullptr, 0,
               relx, E, E, 0, (bid - 392) * 128, 0, E, 0);
    }
}

// ================= per-step GEMM, runtime split-K =================
__global__ __launch_bounds__(256) void k_gru2(
    const float* emb, const float* h,
    const float* Wihc, const float* Whh,
    const float* gixc, const float* bhh,
    float* gip, float* ghp, int giOn, int ksp)
{
    __shared__ GSmem sm;
    int xt = blockIdx.x;
    const int m0 = blockIdx.y * 64;
    const int z  = blockIdx.z;
    const int kt = H / ksp;
    const int kb = z * kt, ke = kb + kt;
    if (giOn && xt < 12){
        gemm64(sm, emb, E, B, Wihc, E, nullptr,
               (z == 0) ? gixc : nullptr, H3,
               gip + (size_t)z * B * H3, H3,
               H3, m0, xt * 128, kb, ke, 0);
    } else {
        if (giOn) xt -= 12;
        gemm64(sm, h, H, B, Whh, H,
               (z == 0) ? bhh : nullptr, nullptr, 0,
               ghp + (size_t)z * B * H3, H3,
               H3, m0, xt * 128, kb, ke, 0);
    }
}

// ====== fused rel step: combine(splitK) + 51 logits + softmax + argmax + NEXT-gi write ======
__global__ __launch_bounds__(256) void k_rel_fused(
    const float* __restrict__ gip, const float* __restrict__ ghp, int ksp,
    const float* __restrict__ hold,
    const float* __restrict__ Wp, const float* __restrict__ bp,
    const float* __restrict__ We, const float* __restrict__ be,
    const float* __restrict__ rel_gi_c,
    const float* __restrict__ gixc_c,
    float* __restrict__ gi_next,
    float* __restrict__ out_rel, int c,
    float* __restrict__ out_act,
    float* __restrict__ hnew_out)
{
    __shared__ float hn[H];
    __shared__ float logits[R + 1];
    __shared__ int   act_sh;
    const int b = blockIdx.x, t = threadIdx.x;
    const int wvi = t >> 6, ln = t & 63;
    const size_t gbase = (size_t)b * H3;
    for (int g = t; g < H; g += 256){
        float ir = 0.f, hr = 0.f, iz = 0.f, hz = 0.f, in_ = 0.f, hnn = 0.f;
        for (int z = 0; z < ksp; ++z){
            const size_t o = (size_t)z * B * H3 + gbase;
            ir  += gip[o + g];        hr  += ghp[o + g];
            iz  += gip[o + H + g];    hz  += ghp[o + H + g];
            in_ += gip[o + 2*H + g];  hnn += ghp[o + 2*H + g];
        }
        const float r = 1.f / (1.f + expf(-(ir + hr)));
        const float z = 1.f / (1.f + expf(-(iz + hz)));
        const float n = tanhf(in_ + r * hnn);
        const float hv = (1.f - z) * n + z * hold[(size_t)b * H + g];
        hn[g] = hv;
        hnew_out[(size_t)b * H + g] = hv;
    }
    __syncthreads();
    for (int i = wvi; i < R + 1; i += 4){
        const float* wr = (i < R) ? Wp + (size_t)i * H : We;
        float a = 0.f;
        #pragma unroll
        for (int u = 0; u < H/64; ++u) a += hn[ln + 64*u] * wr[ln + 64*u];
        a = wred_sum(a);
        if (ln == 0) logits[i] = a + (i < R ? bp[i] : be[0]);
    }
    __syncthreads();
    if (wvi == 0){
        const float v = (ln < R + 1) ? logits[ln] : -INFINITY;
        const float m = wred_maxf(v);
        const float p = v - m;
        const float e = (ln < R + 1) ? expf(p) : 0.f;
        const float lse = logf(wred_sum(e));
        const float q = p - lse;
        float bv = q; int bi = ln;
        #pragma unroll
        for (int o = 32; o > 0; o >>= 1){
            float ov = __shfl_xor(bv, o);
            int   oi = __shfl_xor(bi, o);
            if (ov > bv || (ov == bv && oi < bi)){ bv = ov; bi = oi; }
        }
        if (ln < R + 1)
            out_rel[(size_t)c * B * (R+1) + (size_t)b * (R+1) + ln] = q;
        if (ln == 0){
            out_act[(size_t)(3*c) * B + b] = (float)bi;
            act_sh = bi;
        }
    }
    __syncthreads();
    const float* rg = rel_gi_c + (size_t)act_sh * H3;
    const float* gx = gixc_c + gbase;
    float* go = gi_next + gbase;
    #pragma unroll
    for (int u = 0; u < H3/256; ++u) go[t + 256*u] = rg[t + 256*u] + gx[t + 256*u];
}

// == fused copy step ==
__global__ __launch_bounds__(256) void k_copy_fused(
    const float* __restrict__ gip, const float* __restrict__ ghp,
    int gi_full, int ksp,
    const float* __restrict__ hold,
    const float* __restrict__ v,
    const float* __restrict__ W_fuse, const float* __restrict__ b_fuse,
    const float* __restrict__ W_copy, const float* __restrict__ b_copy,
    const float* __restrict__ We, const float* __restrict__ be,
    const int* __restrict__ sentence, const float* __restrict__ word_emb,
    float* __restrict__ out_copy, int slot,
    float* __restrict__ emb, float* __restrict__ out_act, int aslot,
    float* __restrict__ hnew_out, const float* __restrict__ dec, int cell_end)
{
    __shared__ float hn[H];
    __shared__ float shl[H];
    __shared__ float u_lds[100];
    __shared__ float wc_lds[100];
    __shared__ float sco[101];
    __shared__ int   act_sh;
    const int b = blockIdx.x, t = threadIdx.x;
    const int wvi = t >> 6, ln = t & 63;
    const size_t gbase = (size_t)b * H3;
    for (int g = t; g < H; g += 256){
        float ir, iz, in_;
        if (gi_full){
            ir  = gip[gbase + g];
            iz  = gip[gbase + H + g];
            in_ = gip[gbase + 2*H + g];
        } else {
            ir = 0.f; iz = 0.f; in_ = 0.f;
            for (int z = 0; z < ksp; ++z){
                const size_t o = (size_t)z * B * H3 + gbase;
                ir += gip[o + g]; iz += gip[o + H + g]; in_ += gip[o + 2*H + g];
            }
        }
        float hr = 0.f, hz = 0.f, hnn = 0.f;
        for (int z = 0; z < ksp; ++z){
            const size_t o = (size_t)z * B * H3 + gbase;
            hr += ghp[o + g]; hz += ghp[o + H + g]; hnn += ghp[o + 2*H + g];
        }
        const float r = 1.f / (1.f + expf(-(ir + hr)));
        const float z = 1.f / (1.f + expf(-(iz + hz)));
        const float n = tanhf(in_ + r * hnn);
        const float hv = (1.f - z) * n + z * hold[(size_t)b * H + g];
        hn[g] = hv;
        shl[g] = selu_f(hv);
        hnew_out[(size_t)b * H + g] = cell_end ? 0.5f * (dec[(size_t)b * H + g] + hv) : hv;
    }
    if (t < 100) wc_lds[t] = W_copy[t];
    __syncthreads();
    for (int n = wvi; n < 100; n += 4){
        const float* wr = W_fuse + (size_t)n * (2*H);
        float a = 0.f;
        #pragma unroll
        for (int u = 0; u < H/64; ++u) a += shl[ln + 64*u] * wr[ln + 64*u];
        a = wred_sum(a);
        if (ln == 0) u_lds[n] = a + b_fuse[n];
    }
    if (wvi == 3){
        float a = 0.f;
        #pragma unroll
        for (int u = 0; u < H/64; ++u) a += hn[ln + 64*u] * We[ln + 64*u];
        a = wred_sum(a);
        if (ln == 0) sco[100] = a + be[0];
    }
    __syncthreads();
    const float bc = b_copy[0];
    for (int s = wvi; s < S; s += 4){
        const float* vb = v + ((size_t)b * S + s) * 100;
        float a = selu_f(u_lds[ln] + vb[ln]) * wc_lds[ln];
        if (ln + 64 < 100) a += selu_f(u_lds[ln + 64] + vb[ln + 64]) * wc_lds[ln + 64];
        a = wred_sum(a);
        if (ln == 0) sco[s] = a + bc;
    }
    __syncthreads();
    if (wvi == 0){
        const float v1 = sco[ln];
        const int i2 = ln + 64;
        const float v2 = (i2 <= S) ? sco[i2] : -INFINITY;
        const float m = wred_maxf(fmaxf(v1, v2));
        const float p1 = v1 - m, p2 = v2 - m;
        float e = expf(p1) + ((i2 <= S) ? expf(p2) : 0.f);
        const float lse = logf(wred_sum(e));
        const float q1 = p1 - lse, q2 = p2 - lse;
        float bv; int bi;
        if (q2 > q1){ bv = q2; bi = i2; } else { bv = q1; bi = ln; }
        #pragma unroll
        for (int o = 32; o > 0; o >>= 1){
            float ov = __shfl_xor(bv, o);
            int   oi = __shfl_xor(bi, o);
            if (ov > bv || (ov == bv && oi < bi)){ bv = ov; bi = oi; }
        }
        const size_t obase = (size_t)slot * B * (S+1) + (size_t)b * (S+1);
        out_copy[obase + ln] = q1;
        if (i2 <= S) out_copy[obase + i2] = q2;
        if (ln == 0){
            out_act[(size_t)aslot * B + b] = (float)bi;
            act_sh = bi;
        }
    }
    __syncthreads();
    const int act = act_sh;
    const int wd = sentence[b * S + (act < S ? act : S - 1)];
    const float* wr = word_emb + (size_t)wd * E;
    float* ebp = emb + (size_t)b * E;
    ebp[t] = wr[t];
    ebp[t + 256] = wr[t + 256];
}

extern "C" void kernel_launch(void* const* d_in, const int* in_sizes, int n_in,
                              void* d_out, int out_size, void* d_ws, size_t ws_size,
                              hipStream_t stream)
{
    (void)in_sizes; (void)n_in; (void)out_size;
    const int*   sentence = (const int*)  d_in[0];
    const float* dec      = (const float*)d_in[1];
    const float* enc      = (const float*)d_in[2];
    const float* word_emb = (const float*)d_in[3];
    const float* rel_emb  = (const float*)d_in[4];
    const float* sos      = (const float*)d_in[5];
    const float* W_comb   = (const float*)d_in[6];
    const float* b_comb   = (const float*)d_in[7];
    const float* W_attn   = (const float*)d_in[8];
    // d_in[9] = b_attn (cancels in softmax)
    const float* W_ih     = (const float*)d_in[10];
    const float* W_hh     = (const float*)d_in[11];
    const float* b_ih     = (const float*)d_in[12];
    const float* b_hh     = (const float*)d_in[13];
    const float* W_eos    = (const float*)d_in[14];
    const float* b_eos    = (const float*)d_in[15];
    const float* W_pred   = (const float*)d_in[16];
    const float* b_pred   = (const float*)d_in[17];
    const float* W_fuse   = (const float*)d_in[18];
    const float* b_fuse   = (const float*)d_in[19];
    const float* W_copy   = (const float*)d_in[20];
    const float* b_copy   = (const float*)d_in[21];

    float* out       = (float*)d_out;
    float* out_rel   = out;
    float* out_copy  = out + (size_t)NC * B * (R + 1);
    float* out_act   = out_copy + (size_t)2 * NC * B * (S + 1);

    float* p = (float*)d_ws;
    float* v_buf  = p; p += (size_t)B * S * 100;        // 2.56M
    float* Wihc   = p; p += (size_t)NC * H3 * E;        // 3.93M
    float* gixc   = p; p += (size_t)NC * B * H3;        // 1.97M
    float* rel_gi = p; p += (size_t)NC * 64 * H3;       // 0.49M
    float* WcT    = p; p += (size_t)(H + E) * E;        // 0.52M
    float* relx   = p; p += (size_t)64 * E;
    float* xc     = p; p += B * E;
    float* emb    = p; p += B * E;
    float* hb0    = p; p += B * H;
    float* hb1    = p; p += B * H;
    const size_t fixed_floats = (size_t)(p - (float*)d_ws);
    // runtime split-K: 8 if ws fits, else 4 (deterministic in ws_size)
    int ksp = 8;
    if ((fixed_floats + (size_t)2 * 8 * B * H3) * 4 > ws_size) ksp = 4;
    float* gip = p; p += (size_t)ksp * B * H3;
    float* ghp = p; p += (size_t)ksp * B * H3;
    float* hb[2] = { hb0, hb1 };

    // ---- P0: init + transpose + ctx->xc + rel_x (one launch) ----
    k_pre0<<<396, 256, 0, stream>>>(sos, dec, enc, W_attn, W_comb, b_comb, rel_emb,
                                    emb, hb0, WcT, xc, relx);

    // ---- P1: mega multi-GEMM {Wihc, v_buf, gixc, rel_gi} (one launch) ----
    Jobs4 js;
    // j0: Wihc[c] = W_ih[c] @ Wc1  (A=W_ih, W=WcT rows<512)
    js.j[0] = { W_ih, E, (long long)H3 * E, H3,
                WcT, E, 0, nullptr, 0, nullptr, 0, 0,
                Wihc, E, (long long)H3 * E, E, E, 0, 4, 24, 0 };
    // j1: v_buf = selu(enc) @ Wf2^T
    js.j[1] = { enc, H, 0, B * S,
                W_fuse + H, 2 * H, 0, nullptr, 0, nullptr, 0, 0,
                v_buf, 100, 0, 100, H, 1, 1, 400, 480 };
    // j2: gixc[c] = xc @ W_ih[c]^T + b_ih[c]
    js.j[2] = { xc, E, 0, B,
                W_ih, E, (long long)H3 * E, b_ih, H3, nullptr, 0, 0,
                gixc, H3, (long long)B * H3, H3, E, 0, 12, 4, 880 };
    // j3: rel_gi[c] = rel_x @ W_ih[c]^T
    js.j[3] = { relx, E, 0, R + 1,
                W_ih, E, (long long)H3 * E, nullptr, 0, nullptr, 0, 0,
                rel_gi, H3, (long long)64 * H3, H3, E, 0, 12, 1, 1120 };
    k_mgemm<<<1180, 256, 0, stream>>>(js);

    int cur = 0;
    for (int c = 0; c < NC; ++c){
        const float* Wihc_c = Wihc + (size_t)c * H3 * E;
        const float* Whh_c  = W_hh + (size_t)c * H3 * H;
        const float* gixc_c = gixc + (size_t)c * B * H3;
        const float* bhh_c  = b_hh + (size_t)c * H3;
        for (int t3 = 0; t3 < 3; ++t3){
            const int giOn = (t3 != 1);
            k_gru2<<<dim3(giOn ? 24 : 12, 4, ksp), 256, 0, stream>>>(
                emb, hb[cur], Wihc_c, Whh_c, gixc_c, bhh_c,
                gip, ghp, giOn, ksp);
            if (t3 == 0){
                k_rel_fused<<<B, 256, 0, stream>>>(
                    gip, ghp, ksp, hb[cur], W_pred, b_pred, W_eos, b_eos,
                    rel_gi + (size_t)c * 64 * H3, gixc_c, gip,
                    out_rel, c, out_act, hb[cur^1]);
            } else {
                k_copy_fused<<<B, 256, 0, stream>>>(
                    gip, ghp, (t3 == 1) ? 1 : 0, ksp, hb[cur], v_buf,
                    W_fuse, b_fuse, W_copy, b_copy, W_eos, b_eos,
                    sentence, word_emb,
                    out_copy, 2*c + (t3-1), emb, out_act, 3*c + t3,
                    hb[cur^1], dec, (t3 == 2) ? 1 : 0);
            }
            cur ^= 1;
        }
    }
}